// Round 7
// baseline (546.339 us; speedup 1.0000x reference)
//
#include <hip/hip_runtime.h>

#define THREADS 256
#define NBLK 2048         // 8 blocks/CU x 256 CUs; co-resident via launch_bounds(256,8)
#define GROUPS 64
#define GSIZE (NBLK / GROUPS)   // 32
#define MIRRORS 32
#define BARWORDS ((GROUPS + 1 + MIRRORS) * 16)
#define CAP 128
#define EST_ITERS 4       // 4 iters * 1024 floats = 4096-sample block-local estimate
#define EPS 1e-10
#define THRES 4.0f
#define SMALLN (1 << 23)

typedef float vf4 __attribute__((ext_vector_type(4)));

__device__ __forceinline__ double wave_sum(double v) {
#pragma unroll
  for (int off = 32; off > 0; off >>= 1) v += __shfl_down(v, off, 64);
  return v;
}

// blockDim.x must be 256 (4 waves). Safe to call repeatedly.
__device__ __forceinline__ double block_sum(double v, double* lds) {
  v = wave_sum(v);
  const int lane = threadIdx.x & 63;
  const int wid = threadIdx.x >> 6;
  __syncthreads();
  if (lane == 0) lds[wid] = v;
  __syncthreads();
  return lds[0] + lds[1] + lds[2] + lds[3];
}

// Hierarchical device-scope grid barrier (FALLBACK PATH ONLY — never executed
// when the candidate fast path validates). Single-use (generation value 1).
__device__ __forceinline__ void grid_sync_once(unsigned* bar, int b) {
  __syncthreads();
  if (threadIdx.x == 0) {
    __builtin_amdgcn_fence(__ATOMIC_RELEASE, "agent");
    unsigned* grp = bar + (b / GSIZE) * 16;
    unsigned* root = bar + GROUPS * 16;
    unsigned* mir = bar + (GROUPS + 1) * 16;
    unsigned v = __hip_atomic_fetch_add(grp, 1u, __ATOMIC_ACQ_REL, __HIP_MEMORY_SCOPE_AGENT);
    if (v == GSIZE - 1u) {
      unsigned r = __hip_atomic_fetch_add(root, 1u, __ATOMIC_ACQ_REL, __HIP_MEMORY_SCOPE_AGENT);
      if (r == GROUPS - 1u) {
#pragma unroll
        for (int m = 0; m < MIRRORS; ++m)
          __hip_atomic_store(mir + m * 16, 1u, __ATOMIC_RELEASE, __HIP_MEMORY_SCOPE_AGENT);
      }
    }
    unsigned* mymir = mir + (b & (MIRRORS - 1)) * 16;
    while (__hip_atomic_load(mymir, __ATOMIC_RELAXED, __HIP_MEMORY_SCOPE_AGENT) < 1u) {
      __builtin_amdgcn_s_sleep(32);
    }
    __builtin_amdgcn_fence(__ATOMIC_ACQUIRE, "agent");
  }
  __syncthreads();
}

// ---- K1: per-slab scan: sum/ss (double) + candidate collection ----
__global__ void __launch_bounds__(THREADS, 8) k_scan(
    const float* __restrict__ x, long n, unsigned* __restrict__ bar,
    double* __restrict__ pS, double* __restrict__ pSS,
    double* __restrict__ pM, double* __restrict__ pT, int* __restrict__ pO,
    int* __restrict__ counts, float* __restrict__ slices) {
  __shared__ double lds[4];
  __shared__ float lcand[CAP];
  __shared__ int lcnt;
  const int b = blockIdx.x;
  const long nv4 = n >> 2;
  const long vpb = (nv4 + NBLK - 1) / NBLK;
  const long v0 = (long)b * vpb;
  long v1 = v0 + vpb;
  if (v1 > nv4) v1 = nv4;
  const float4* xv = (const float4*)x;
  const bool last = (b == NBLK - 1);

  if (b == 0) {  // zero fallback-barrier state (kernel boundary orders vs K2)
    for (int i = threadIdx.x; i < BARWORDS; i += THREADS) bar[i] = 0u;
  }
  if (threadIdx.x == 0) lcnt = 0;
  __syncthreads();

  // Block-local estimate over the first EST_ITERS strides (re-read hits L1/L2)
  double es = 0.0, ess = 0.0;
  long iter_end = v0 + (long)EST_ITERS * THREADS;
  if (iter_end > v1) iter_end = v1;
  for (long i = v0 + threadIdx.x; i < iter_end; i += THREADS) {
    float4 v = xv[i];
    double a = v.x, bb = v.y, c = v.z, d = v.w;
    es += (a + bb) + (c + d);
    ess += (a * a + bb * bb) + (c * c + d * d);
  }
  es = block_sum(es, lds);
  ess = block_sum(ess, lds);
  const long ecount = (iter_end - v0) * 4;
  double mhat = 0.0, th = 0.0;
  int ovf = 0;
  if (ecount >= 4096) {
    double ne = (double)ecount;
    mhat = es / ne;
    double var = (ess - es * es / ne) / (ne - 1.0);
    double sig = var > 0.0 ? sqrt(var) : 0.0;
    th = 3.2 * sig;
    if (!(th > 0.0)) ovf = 1;
  } else {
    ovf = 1;
  }
  const float mhf = (float)mhat;
  const float thf = (float)th;

  // Main scan
  double s = 0.0, ss = 0.0;
  {
    long i = v0 + threadIdx.x;
    const long span = v1 - v0;
    const long nfull = v0 + (span / (2 * THREADS)) * (2 * THREADS);
    for (; i < nfull; i += 2 * THREADS) {
      float4 va = xv[i];
      float4 vb = xv[i + THREADS];
      double a0 = va.x, a1 = va.y, a2 = va.z, a3 = va.w;
      double b0 = vb.x, b1 = vb.y, b2 = vb.z, b3 = vb.w;
      s += ((a0 + a1) + (a2 + a3)) + ((b0 + b1) + (b2 + b3));
      ss += ((a0 * a0 + a1 * a1) + (a2 * a2 + a3 * a3)) +
            ((b0 * b0 + b1 * b1) + (b2 * b2 + b3 * b3));
      if (fabsf(va.x - mhf) > thf) { int k = atomicAdd(&lcnt, 1); if (k < CAP) lcand[k] = va.x; }
      if (fabsf(va.y - mhf) > thf) { int k = atomicAdd(&lcnt, 1); if (k < CAP) lcand[k] = va.y; }
      if (fabsf(va.z - mhf) > thf) { int k = atomicAdd(&lcnt, 1); if (k < CAP) lcand[k] = va.z; }
      if (fabsf(va.w - mhf) > thf) { int k = atomicAdd(&lcnt, 1); if (k < CAP) lcand[k] = va.w; }
      if (fabsf(vb.x - mhf) > thf) { int k = atomicAdd(&lcnt, 1); if (k < CAP) lcand[k] = vb.x; }
      if (fabsf(vb.y - mhf) > thf) { int k = atomicAdd(&lcnt, 1); if (k < CAP) lcand[k] = vb.y; }
      if (fabsf(vb.z - mhf) > thf) { int k = atomicAdd(&lcnt, 1); if (k < CAP) lcand[k] = vb.z; }
      if (fabsf(vb.w - mhf) > thf) { int k = atomicAdd(&lcnt, 1); if (k < CAP) lcand[k] = vb.w; }
    }
    for (; i < v1; i += THREADS) {
      float4 v = xv[i];
      double a = v.x, bb = v.y, c = v.z, d = v.w;
      s += (a + bb) + (c + d);
      ss += (a * a + bb * bb) + (c * c + d * d);
      if (fabsf(v.x - mhf) > thf) { int k = atomicAdd(&lcnt, 1); if (k < CAP) lcand[k] = v.x; }
      if (fabsf(v.y - mhf) > thf) { int k = atomicAdd(&lcnt, 1); if (k < CAP) lcand[k] = v.y; }
      if (fabsf(v.z - mhf) > thf) { int k = atomicAdd(&lcnt, 1); if (k < CAP) lcand[k] = v.z; }
      if (fabsf(v.w - mhf) > thf) { int k = atomicAdd(&lcnt, 1); if (k < CAP) lcand[k] = v.w; }
    }
    if (last) {
      for (long j = nv4 * 4 + threadIdx.x; j < n; j += THREADS) {
        float f = x[j];
        double a = f;
        s += a;
        ss += a * a;
        if (fabsf(f - mhf) > thf) { int k = atomicAdd(&lcnt, 1); if (k < CAP) lcand[k] = f; }
      }
    }
  }
  s = block_sum(s, lds);  // syncs make lcnt/lcand visible
  ss = block_sum(ss, lds);
  if (threadIdx.x == 0) {
    pS[b] = s;
    pSS[b] = ss;
    pM[b] = mhat;
    pT[b] = th;
    pO[b] = (ovf || lcnt > CAP) ? 1 : 0;
    counts[b] = lcnt < CAP ? lcnt : CAP;
  }
  int c = lcnt < CAP ? lcnt : CAP;
  for (int t = threadIdx.x; t < c; t += THREADS)
    slices[(size_t)b * CAP + t] = lcand[t];
}

// ---- K2: redundant finalize (pass1 + coverage + outliers -> m2,r2) + apply ----
__global__ void __launch_bounds__(THREADS, 8) k_final(
    const float* __restrict__ x, float* __restrict__ out, long n,
    const float* __restrict__ gamma, const float* __restrict__ beta,
    unsigned* __restrict__ bar,
    const double* __restrict__ pS, const double* __restrict__ pSS,
    const double* __restrict__ pM, const double* __restrict__ pT,
    const int* __restrict__ pO,
    const int* __restrict__ counts, const float* __restrict__ slices,
    double* __restrict__ pD, double* __restrict__ pE, double* __restrict__ pF) {
  __shared__ double lds[4];
  const int b = blockIdx.x;
  const long nv4 = n >> 2;
  const long vpb = (nv4 + NBLK - 1) / NBLK;
  const long v0 = (long)b * vpb;
  long v1 = v0 + vpb;
  if (v1 > nv4) v1 = nv4;
  const float4* xv = (const float4*)x;
  const bool last = (b == NBLK - 1);

  // Redundant pass-1 finalize (identical deterministic result in every block)
  double gs = 0.0, gss = 0.0;
  for (int i = threadIdx.x; i < NBLK; i += THREADS) { gs += pS[i]; gss += pSS[i]; }
  gs = block_sum(gs, lds);
  gss = block_sum(gss, lds);
  const double nd = (double)n;
  const double mean1 = gs / nd;
  const double var1 = (gss - gs * gs / nd) / (nd - 1.0);
  const double r1d = 1.0 / sqrt(var1 + EPS);
  double bad = 0.0;
  for (int i = threadIdx.x; i < NBLK; i += THREADS) {
    double cond = (pT[i] + fabs(mean1 - pM[i])) * r1d;
    if (pO[i] != 0 || !(cond < 3.999)) bad += 1.0;
  }
  bad = block_sum(bad, lds);
  const bool fast = (bad == 0.0);
  const float m1f = (float)mean1;
  const float r1f = (float)r1d;

  double s2, ss2, c2;
  if (fast) {
    // Redundant outlier gather over the compact candidate buffer (~4K floats)
    double os = 0.0, oss = 0.0, oc = 0.0;
    for (int i = threadIdx.x; i < NBLK; i += THREADS) {
      int c = counts[i];
      if (c > CAP) c = CAP;
      const float* sl = slices + (size_t)i * CAP;
      for (int j = 0; j < c; ++j) {
        float v = sl[j];
        float nf = (v - m1f) * r1f;
        if (!(nf < THRES && nf > -THRES)) {  // exact reference rule
          double a = v;
          os += a;
          oss += a * a;
          oc += 1.0;
        }
      }
    }
    os = block_sum(os, lds);
    oss = block_sum(oss, lds);
    oc = block_sum(oc, lds);
    s2 = gs - os;
    ss2 = gss - oss;
    c2 = nd - oc;
  } else {
    // Fallback: full masked rescan of own slab + one grid barrier (rare)
    double os = 0.0, oss = 0.0, oc = 0.0;
    for (long i = v0 + threadIdx.x; i < v1; i += THREADS) {
      float4 v = xv[i];
      float nf;
      nf = (v.x - m1f) * r1f;
      if (nf < THRES && nf > -THRES) { double a = v.x; os += a; oss += a * a; oc += 1.0; }
      nf = (v.y - m1f) * r1f;
      if (nf < THRES && nf > -THRES) { double a = v.y; os += a; oss += a * a; oc += 1.0; }
      nf = (v.z - m1f) * r1f;
      if (nf < THRES && nf > -THRES) { double a = v.z; os += a; oss += a * a; oc += 1.0; }
      nf = (v.w - m1f) * r1f;
      if (nf < THRES && nf > -THRES) { double a = v.w; os += a; oss += a * a; oc += 1.0; }
    }
    if (last) {
      for (long j = nv4 * 4 + threadIdx.x; j < n; j += THREADS) {
        float f = x[j];
        float nf = (f - m1f) * r1f;
        if (nf < THRES && nf > -THRES) { double a = f; os += a; oss += a * a; oc += 1.0; }
      }
    }
    os = block_sum(os, lds);
    oss = block_sum(oss, lds);
    oc = block_sum(oc, lds);
    if (threadIdx.x == 0) { pD[b] = os; pE[b] = oss; pF[b] = oc; }
    grid_sync_once(bar, b);
    double t1 = 0.0, t2 = 0.0, t3 = 0.0;
    for (int i = threadIdx.x; i < NBLK; i += THREADS) { t1 += pD[i]; t2 += pE[i]; t3 += pF[i]; }
    s2 = block_sum(t1, lds);
    ss2 = block_sum(t2, lds);
    c2 = block_sum(t3, lds);
  }

  const double mean2 = s2 / c2;
  const double var2 = (ss2 - s2 * s2 / c2) / (c2 - 1.0);
  const float m2f = (float)mean2;
  const float r2f = (float)(1.0 / sqrt(var2 + EPS));
  const float g = gamma[0];
  const float bb = beta[0];
  float4* ov = (float4*)out;
  {
    long i = v0 + threadIdx.x;
    const long span = v1 - v0;
    const long nfull = v0 + (span / (2 * THREADS)) * (2 * THREADS);
    for (; i < nfull; i += 2 * THREADS) {
      float4 va = xv[i];
      float4 vb = xv[i + THREADS];
      vf4 ta, tb;
      ta.x = g * (va.x - m2f) * r2f + bb;
      ta.y = g * (va.y - m2f) * r2f + bb;
      ta.z = g * (va.z - m2f) * r2f + bb;
      ta.w = g * (va.w - m2f) * r2f + bb;
      tb.x = g * (vb.x - m2f) * r2f + bb;
      tb.y = g * (vb.y - m2f) * r2f + bb;
      tb.z = g * (vb.z - m2f) * r2f + bb;
      tb.w = g * (vb.w - m2f) * r2f + bb;
      __builtin_nontemporal_store(ta, (vf4*)&ov[i]);
      __builtin_nontemporal_store(tb, (vf4*)&ov[i + THREADS]);
    }
    for (; i < v1; i += THREADS) {
      float4 v = xv[i];
      vf4 t;
      t.x = g * (v.x - m2f) * r2f + bb;
      t.y = g * (v.y - m2f) * r2f + bb;
      t.z = g * (v.z - m2f) * r2f + bb;
      t.w = g * (v.w - m2f) * r2f + bb;
      __builtin_nontemporal_store(t, (vf4*)&ov[i]);
    }
  }
  if (last) {
    for (long j = nv4 * 4 + threadIdx.x; j < n; j += THREADS) {
      float t = g * (x[j] - m2f) * r2f + bb;
      __builtin_nontemporal_store(t, &out[j]);
    }
  }
}

// ---------------- small-n fallback pipeline (scalar, robust) ----------------
__global__ void __launch_bounds__(THREADS) k_r1(
    const float* __restrict__ x, long n, double* __restrict__ pA, double* __restrict__ pB) {
  __shared__ double lds[4];
  double s = 0.0, ss = 0.0;
  const long stride = (long)gridDim.x * blockDim.x;
  for (long i = (long)blockIdx.x * blockDim.x + threadIdx.x; i < n; i += stride) {
    double a = x[i];
    s += a;
    ss += a * a;
  }
  s = block_sum(s, lds);
  ss = block_sum(ss, lds);
  if (threadIdx.x == 0) { pA[blockIdx.x] = s; pB[blockIdx.x] = ss; }
}

__global__ void __launch_bounds__(THREADS) k_f1(
    const double* __restrict__ pA, const double* __restrict__ pB, int nblk,
    double n, double* __restrict__ fin) {
  __shared__ double lds[4];
  double s = 0.0, ss = 0.0;
  for (int i = threadIdx.x; i < nblk; i += blockDim.x) { s += pA[i]; ss += pB[i]; }
  s = block_sum(s, lds);
  ss = block_sum(ss, lds);
  if (threadIdx.x == 0) {
    double mean1 = s / n;
    double var1 = (ss - s * s / n) / (n - 1.0);
    fin[0] = mean1;
    fin[1] = 1.0 / sqrt(var1 + EPS);
  }
}

__global__ void __launch_bounds__(THREADS) k_r2(
    const float* __restrict__ x, long n, const double* __restrict__ fin,
    double* __restrict__ pA, double* __restrict__ pB, double* __restrict__ pC) {
  __shared__ double lds[4];
  const float m1 = (float)fin[0];
  const float r1 = (float)fin[1];
  double s = 0.0, ss = 0.0, c = 0.0;
  const long stride = (long)gridDim.x * blockDim.x;
  for (long i = (long)blockIdx.x * blockDim.x + threadIdx.x; i < n; i += stride) {
    float f = x[i];
    float nf = (f - m1) * r1;
    if (nf < THRES && nf > -THRES) { double a = f; s += a; ss += a * a; c += 1.0; }
  }
  s = block_sum(s, lds);
  ss = block_sum(ss, lds);
  c = block_sum(c, lds);
  if (threadIdx.x == 0) { pA[blockIdx.x] = s; pB[blockIdx.x] = ss; pC[blockIdx.x] = c; }
}

__global__ void __launch_bounds__(THREADS) k_f2(
    const double* __restrict__ pA, const double* __restrict__ pB,
    const double* __restrict__ pC, int nblk, double* __restrict__ fin) {
  __shared__ double lds[4];
  double s = 0.0, ss = 0.0, c = 0.0;
  for (int i = threadIdx.x; i < nblk; i += blockDim.x) { s += pA[i]; ss += pB[i]; c += pC[i]; }
  s = block_sum(s, lds);
  ss = block_sum(ss, lds);
  c = block_sum(c, lds);
  if (threadIdx.x == 0) {
    double mean2 = s / c;
    double var2 = (ss - s * s / c) / (c - 1.0);
    fin[2] = mean2;
    fin[3] = 1.0 / sqrt(var2 + EPS);
  }
}

__global__ void __launch_bounds__(THREADS) k_ap(
    const float* __restrict__ x, float* __restrict__ out, long n,
    const double* __restrict__ fin,
    const float* __restrict__ gamma, const float* __restrict__ beta) {
  const float m2 = (float)fin[2];
  const float r2 = (float)fin[3];
  const float g = gamma[0];
  const float bb = beta[0];
  const long stride = (long)gridDim.x * blockDim.x;
  for (long i = (long)blockIdx.x * blockDim.x + threadIdx.x; i < n; i += stride) {
    out[i] = g * (x[i] - m2) * r2 + bb;
  }
}

extern "C" void kernel_launch(void* const* d_in, const int* in_sizes, int n_in,
                              void* d_out, int out_size, void* d_ws, size_t ws_size,
                              hipStream_t stream) {
  const float* x = (const float*)d_in[0];
  const float* gamma = (const float*)d_in[1];
  const float* beta = (const float*)d_in[2];
  float* out = (float*)d_out;
  const long n = (long)in_sizes[0];

  char* base = (char*)d_ws;
  unsigned* bar = (unsigned*)base;                 // BARWORDS uints (~6.2 KB)
  double* pS = (double*)(base + 16384);
  double* pSS = pS + NBLK;
  double* pM = pSS + NBLK;
  double* pT = pM + NBLK;
  double* pD = pT + NBLK;
  double* pE = pD + NBLK;
  double* pF = pE + NBLK;
  int* pO = (int*)(pF + NBLK);
  int* counts = pO + NBLK;
  float* slices = (float*)(counts + NBLK);
  size_t needed = (size_t)((char*)(slices + (size_t)NBLK * CAP) - base);

  if (n >= SMALLN && n >= (long)NBLK * 16384 && ws_size >= needed) {
    k_scan<<<NBLK, THREADS, 0, stream>>>(x, n, bar, pS, pSS, pM, pT, pO, counts, slices);
    k_final<<<NBLK, THREADS, 0, stream>>>(x, out, n, gamma, beta, bar,
                                          pS, pSS, pM, pT, pO, counts, slices, pD, pE, pF);
  } else {
    // small-n scalar pipeline
    int nblk = 64;
    double* fin = (double*)(base);        // 4 doubles
    double* fA = (double*)(base + 256);
    double* fB = fA + nblk;
    double* fC = fB + nblk;
    k_r1<<<nblk, THREADS, 0, stream>>>(x, n, fA, fB);
    k_f1<<<1, THREADS, 0, stream>>>(fA, fB, nblk, (double)n, fin);
    k_r2<<<nblk, THREADS, 0, stream>>>(x, n, fin, fA, fB, fC);
    k_f2<<<1, THREADS, 0, stream>>>(fA, fB, fC, nblk, fin);
    k_ap<<<nblk, THREADS, 0, stream>>>(x, out, n, fin, gamma, beta);
  }
}

// Round 8
// 267.154 us; speedup vs baseline: 2.0450x; 2.0450x over previous
//
#include <hip/hip_runtime.h>

#define THREADS 256
#define NBLK 2048         // 8 blocks/CU x 256 CUs; co-resident via launch_bounds(256,8)
#define GROUPS 64
#define GSIZE (NBLK / GROUPS)   // 32
#define MIRRORS 32
#define BARWORDS ((GROUPS + 1 + MIRRORS) * 16)
#define CAP 128           // power of 2 (shift by 7 below)
#define EST_ITERS 4       // 4 iters * 1024 floats = 4096-sample block-local estimate
#define EPS 1e-10
#define THRES 4.0f
#define SMALLN (1 << 23)

typedef float vf4 __attribute__((ext_vector_type(4)));

__device__ __forceinline__ double wave_sum(double v) {
#pragma unroll
  for (int off = 32; off > 0; off >>= 1) v += __shfl_down(v, off, 64);
  return v;
}

// blockDim.x must be 256 (4 waves).
__device__ __forceinline__ double block_sum(double v, double* lds) {
  v = wave_sum(v);
  const int lane = threadIdx.x & 63;
  const int wid = threadIdx.x >> 6;
  __syncthreads();
  if (lane == 0) lds[wid] = v;
  __syncthreads();
  return lds[0] + lds[1] + lds[2] + lds[3];
}

// blockDim.x must be 1024 (16 waves).
__device__ __forceinline__ double block_sum16(double v, double* lds) {
  v = wave_sum(v);
  const int lane = threadIdx.x & 63;
  const int wid = threadIdx.x >> 6;
  __syncthreads();
  if (lane == 0) lds[wid] = v;
  __syncthreads();
  double r = 0.0;
#pragma unroll
  for (int i = 0; i < 16; ++i) r += lds[i];
  return r;
}

// Hierarchical device-scope grid barrier (FALLBACK PATH ONLY). Single-use.
__device__ __forceinline__ void grid_sync_once(unsigned* bar, int b) {
  __syncthreads();
  if (threadIdx.x == 0) {
    __builtin_amdgcn_fence(__ATOMIC_RELEASE, "agent");
    unsigned* grp = bar + (b / GSIZE) * 16;
    unsigned* root = bar + GROUPS * 16;
    unsigned* mir = bar + (GROUPS + 1) * 16;
    unsigned v = __hip_atomic_fetch_add(grp, 1u, __ATOMIC_ACQ_REL, __HIP_MEMORY_SCOPE_AGENT);
    if (v == GSIZE - 1u) {
      unsigned r = __hip_atomic_fetch_add(root, 1u, __ATOMIC_ACQ_REL, __HIP_MEMORY_SCOPE_AGENT);
      if (r == GROUPS - 1u) {
#pragma unroll
        for (int m = 0; m < MIRRORS; ++m)
          __hip_atomic_store(mir + m * 16, 1u, __ATOMIC_RELEASE, __HIP_MEMORY_SCOPE_AGENT);
      }
    }
    unsigned* mymir = mir + (b & (MIRRORS - 1)) * 16;
    while (__hip_atomic_load(mymir, __ATOMIC_RELAXED, __HIP_MEMORY_SCOPE_AGENT) < 1u) {
      __builtin_amdgcn_s_sleep(32);
    }
    __builtin_amdgcn_fence(__ATOMIC_ACQUIRE, "agent");
  }
  __syncthreads();
}

// ---- K1: per-slab scan: sum/ss (double) + candidate collection ----
__global__ void __launch_bounds__(THREADS, 8) k_scan(
    const float* __restrict__ x, long n, unsigned* __restrict__ bar,
    double* __restrict__ pS, double* __restrict__ pSS,
    double* __restrict__ pM, double* __restrict__ pT, int* __restrict__ pO,
    int* __restrict__ counts, float* __restrict__ slices) {
  __shared__ double lds[4];
  __shared__ float lcand[CAP];
  __shared__ int lcnt;
  const int b = blockIdx.x;
  const long nv4 = n >> 2;
  const long vpb = (nv4 + NBLK - 1) / NBLK;
  const long v0 = (long)b * vpb;
  long v1 = v0 + vpb;
  if (v1 > nv4) v1 = nv4;
  const float4* xv = (const float4*)x;
  const bool last = (b == NBLK - 1);

  if (b == 0) {  // zero fallback-barrier state (kernel boundary orders vs K3)
    for (int i = threadIdx.x; i < BARWORDS; i += THREADS) bar[i] = 0u;
  }
  if (threadIdx.x == 0) lcnt = 0;
  __syncthreads();

  // Block-local estimate over the first EST_ITERS strides (re-read hits L1/L2)
  double es = 0.0, ess = 0.0;
  long iter_end = v0 + (long)EST_ITERS * THREADS;
  if (iter_end > v1) iter_end = v1;
  for (long i = v0 + threadIdx.x; i < iter_end; i += THREADS) {
    float4 v = xv[i];
    double a = v.x, bb = v.y, c = v.z, d = v.w;
    es += (a + bb) + (c + d);
    ess += (a * a + bb * bb) + (c * c + d * d);
  }
  es = block_sum(es, lds);
  ess = block_sum(ess, lds);
  const long ecount = (iter_end - v0) * 4;
  double mhat = 0.0, th = 0.0;
  int ovf = 0;
  if (ecount >= 4096) {
    double ne = (double)ecount;
    mhat = es / ne;
    double var = (ess - es * es / ne) / (ne - 1.0);
    double sig = var > 0.0 ? sqrt(var) : 0.0;
    th = 3.2 * sig;
    if (!(th > 0.0)) ovf = 1;
  } else {
    ovf = 1;
  }
  const float mhf = (float)mhat;
  const float thf = (float)th;

  // Main scan
  double s = 0.0, ss = 0.0;
  {
    long i = v0 + threadIdx.x;
    const long span = v1 - v0;
    const long nfull = v0 + (span / (2 * THREADS)) * (2 * THREADS);
    for (; i < nfull; i += 2 * THREADS) {
      float4 va = xv[i];
      float4 vb = xv[i + THREADS];
      double a0 = va.x, a1 = va.y, a2 = va.z, a3 = va.w;
      double b0 = vb.x, b1 = vb.y, b2 = vb.z, b3 = vb.w;
      s += ((a0 + a1) + (a2 + a3)) + ((b0 + b1) + (b2 + b3));
      ss += ((a0 * a0 + a1 * a1) + (a2 * a2 + a3 * a3)) +
            ((b0 * b0 + b1 * b1) + (b2 * b2 + b3 * b3));
      if (fabsf(va.x - mhf) > thf) { int k = atomicAdd(&lcnt, 1); if (k < CAP) lcand[k] = va.x; }
      if (fabsf(va.y - mhf) > thf) { int k = atomicAdd(&lcnt, 1); if (k < CAP) lcand[k] = va.y; }
      if (fabsf(va.z - mhf) > thf) { int k = atomicAdd(&lcnt, 1); if (k < CAP) lcand[k] = va.z; }
      if (fabsf(va.w - mhf) > thf) { int k = atomicAdd(&lcnt, 1); if (k < CAP) lcand[k] = va.w; }
      if (fabsf(vb.x - mhf) > thf) { int k = atomicAdd(&lcnt, 1); if (k < CAP) lcand[k] = vb.x; }
      if (fabsf(vb.y - mhf) > thf) { int k = atomicAdd(&lcnt, 1); if (k < CAP) lcand[k] = vb.y; }
      if (fabsf(vb.z - mhf) > thf) { int k = atomicAdd(&lcnt, 1); if (k < CAP) lcand[k] = vb.z; }
      if (fabsf(vb.w - mhf) > thf) { int k = atomicAdd(&lcnt, 1); if (k < CAP) lcand[k] = vb.w; }
    }
    for (; i < v1; i += THREADS) {
      float4 v = xv[i];
      double a = v.x, bb = v.y, c = v.z, d = v.w;
      s += (a + bb) + (c + d);
      ss += (a * a + bb * bb) + (c * c + d * d);
      if (fabsf(v.x - mhf) > thf) { int k = atomicAdd(&lcnt, 1); if (k < CAP) lcand[k] = v.x; }
      if (fabsf(v.y - mhf) > thf) { int k = atomicAdd(&lcnt, 1); if (k < CAP) lcand[k] = v.y; }
      if (fabsf(v.z - mhf) > thf) { int k = atomicAdd(&lcnt, 1); if (k < CAP) lcand[k] = v.z; }
      if (fabsf(v.w - mhf) > thf) { int k = atomicAdd(&lcnt, 1); if (k < CAP) lcand[k] = v.w; }
    }
    if (last) {
      for (long j = nv4 * 4 + threadIdx.x; j < n; j += THREADS) {
        float f = x[j];
        double a = f;
        s += a;
        ss += a * a;
        if (fabsf(f - mhf) > thf) { int k = atomicAdd(&lcnt, 1); if (k < CAP) lcand[k] = f; }
      }
    }
  }
  s = block_sum(s, lds);  // syncs make lcnt/lcand visible
  ss = block_sum(ss, lds);
  if (threadIdx.x == 0) {
    pS[b] = s;
    pSS[b] = ss;
    pM[b] = mhat;
    pT[b] = th;
    pO[b] = (ovf || lcnt > CAP) ? 1 : 0;
    counts[b] = lcnt < CAP ? lcnt : CAP;
  }
  int c = lcnt < CAP ? lcnt : CAP;
  for (int t = threadIdx.x; t < c; t += THREADS)
    slices[(size_t)b * CAP + t] = lcand[t];
}

// ---- K2: single-block finalize: pass1 stats, coverage, outlier gather ----
// fin: [0]=mean2 [1]=r2 [2]=fastflag [3]=mean1 [4]=r1
__global__ void __launch_bounds__(1024) k_mid(
    long n,
    const double* __restrict__ pS, const double* __restrict__ pSS,
    const double* __restrict__ pM, const double* __restrict__ pT,
    const int* __restrict__ pO, const int* __restrict__ counts,
    const float* __restrict__ slices, double* __restrict__ fin) {
  __shared__ double lds[16];
  __shared__ int lcounts[NBLK];
  for (int i = threadIdx.x; i < NBLK; i += 1024) {
    int c = counts[i];
    lcounts[i] = c > CAP ? CAP : c;
  }
  double gs = 0.0, gss = 0.0;
  for (int i = threadIdx.x; i < NBLK; i += 1024) { gs += pS[i]; gss += pSS[i]; }
  gs = block_sum16(gs, lds);
  gss = block_sum16(gss, lds);
  const double nd = (double)n;
  const double mean1 = gs / nd;
  const double var1 = (gss - gs * gs / nd) / (nd - 1.0);
  const double r1d = 1.0 / sqrt(var1 + EPS);
  double bad = 0.0;
  for (int i = threadIdx.x; i < NBLK; i += 1024) {
    double cond = (pT[i] + fabs(mean1 - pM[i])) * r1d;
    if (pO[i] != 0 || !(cond < 3.999)) bad += 1.0;
  }
  bad = block_sum16(bad, lds);
  const float m1f = (float)mean1;
  const float r1f = (float)r1d;

  // Coalesced flat scan of the candidate buffer (counts from LDS)
  double os = 0.0, oss = 0.0, oc = 0.0;
  const int total = NBLK * CAP;
  for (int idx = threadIdx.x; idx < total; idx += 1024) {
    int sl = idx >> 7;       // /CAP
    int j = idx & (CAP - 1); // %CAP
    if (j < lcounts[sl]) {
      float v = slices[idx];
      float nf = (v - m1f) * r1f;
      if (!(nf < THRES && nf > -THRES)) {  // exact reference rule
        double a = v;
        os += a;
        oss += a * a;
        oc += 1.0;
      }
    }
  }
  os = block_sum16(os, lds);
  oss = block_sum16(oss, lds);
  oc = block_sum16(oc, lds);

  if (threadIdx.x == 0) {
    const bool fast = (bad == 0.0);
    double mean2 = 0.0, r2 = 0.0;
    if (fast) {
      double s2 = gs - os;
      double ss2 = gss - oss;
      double c2 = nd - oc;
      mean2 = s2 / c2;
      double var2 = (ss2 - s2 * s2 / c2) / (c2 - 1.0);
      r2 = 1.0 / sqrt(var2 + EPS);
    }
    fin[0] = mean2;
    fin[1] = r2;
    fin[2] = fast ? 1.0 : 0.0;
    fin[3] = mean1;
    fin[4] = r1d;
  }
}

// ---- K3: apply (fast path: pure stream; fallback: rescan + barrier) ----
__global__ void __launch_bounds__(THREADS, 8) k_final(
    const float* __restrict__ x, float* __restrict__ out, long n,
    const float* __restrict__ gamma, const float* __restrict__ beta,
    unsigned* __restrict__ bar, const double* __restrict__ fin,
    double* __restrict__ pD, double* __restrict__ pE, double* __restrict__ pF) {
  __shared__ double lds[4];
  const int b = blockIdx.x;
  const long nv4 = n >> 2;
  const long vpb = (nv4 + NBLK - 1) / NBLK;
  const long v0 = (long)b * vpb;
  long v1 = v0 + vpb;
  if (v1 > nv4) v1 = nv4;
  const float4* xv = (const float4*)x;
  const bool last = (b == NBLK - 1);
  const bool fast = (fin[2] != 0.0);

  double mean2, r2d;
  if (fast) {
    mean2 = fin[0];
    r2d = fin[1];
  } else {
    // Fallback: full masked rescan of own slab + one grid barrier (rare)
    const float m1f = (float)fin[3];
    const float r1f = (float)fin[4];
    double os = 0.0, oss = 0.0, oc = 0.0;
    for (long i = v0 + threadIdx.x; i < v1; i += THREADS) {
      float4 v = xv[i];
      float nf;
      nf = (v.x - m1f) * r1f;
      if (nf < THRES && nf > -THRES) { double a = v.x; os += a; oss += a * a; oc += 1.0; }
      nf = (v.y - m1f) * r1f;
      if (nf < THRES && nf > -THRES) { double a = v.y; os += a; oss += a * a; oc += 1.0; }
      nf = (v.z - m1f) * r1f;
      if (nf < THRES && nf > -THRES) { double a = v.z; os += a; oss += a * a; oc += 1.0; }
      nf = (v.w - m1f) * r1f;
      if (nf < THRES && nf > -THRES) { double a = v.w; os += a; oss += a * a; oc += 1.0; }
    }
    if (last) {
      for (long j = nv4 * 4 + threadIdx.x; j < n; j += THREADS) {
        float f = x[j];
        float nf = (f - m1f) * r1f;
        if (nf < THRES && nf > -THRES) { double a = f; os += a; oss += a * a; oc += 1.0; }
      }
    }
    os = block_sum(os, lds);
    oss = block_sum(oss, lds);
    oc = block_sum(oc, lds);
    if (threadIdx.x == 0) { pD[b] = os; pE[b] = oss; pF[b] = oc; }
    grid_sync_once(bar, b);
    double t1 = 0.0, t2 = 0.0, t3 = 0.0;
    for (int i = threadIdx.x; i < NBLK; i += THREADS) { t1 += pD[i]; t2 += pE[i]; t3 += pF[i]; }
    double s2 = block_sum(t1, lds);
    double ss2 = block_sum(t2, lds);
    double c2 = block_sum(t3, lds);
    mean2 = s2 / c2;
    double var2 = (ss2 - s2 * s2 / c2) / (c2 - 1.0);
    r2d = 1.0 / sqrt(var2 + EPS);
  }

  const float m2f = (float)mean2;
  const float r2f = (float)r2d;
  const float g = gamma[0];
  const float bb = beta[0];
  float4* ov = (float4*)out;
  {
    long i = v0 + threadIdx.x;
    const long span = v1 - v0;
    const long nfull = v0 + (span / (2 * THREADS)) * (2 * THREADS);
    for (; i < nfull; i += 2 * THREADS) {
      float4 va = xv[i];
      float4 vb = xv[i + THREADS];
      vf4 ta, tb;
      ta.x = g * (va.x - m2f) * r2f + bb;
      ta.y = g * (va.y - m2f) * r2f + bb;
      ta.z = g * (va.z - m2f) * r2f + bb;
      ta.w = g * (va.w - m2f) * r2f + bb;
      tb.x = g * (vb.x - m2f) * r2f + bb;
      tb.y = g * (vb.y - m2f) * r2f + bb;
      tb.z = g * (vb.z - m2f) * r2f + bb;
      tb.w = g * (vb.w - m2f) * r2f + bb;
      __builtin_nontemporal_store(ta, (vf4*)&ov[i]);
      __builtin_nontemporal_store(tb, (vf4*)&ov[i + THREADS]);
    }
    for (; i < v1; i += THREADS) {
      float4 v = xv[i];
      vf4 t;
      t.x = g * (v.x - m2f) * r2f + bb;
      t.y = g * (v.y - m2f) * r2f + bb;
      t.z = g * (v.z - m2f) * r2f + bb;
      t.w = g * (v.w - m2f) * r2f + bb;
      __builtin_nontemporal_store(t, (vf4*)&ov[i]);
    }
  }
  if (last) {
    for (long j = nv4 * 4 + threadIdx.x; j < n; j += THREADS) {
      float t = g * (x[j] - m2f) * r2f + bb;
      __builtin_nontemporal_store(t, &out[j]);
    }
  }
}

// ---------------- small-n fallback pipeline (scalar, robust) ----------------
__global__ void __launch_bounds__(THREADS) k_r1(
    const float* __restrict__ x, long n, double* __restrict__ pA, double* __restrict__ pB) {
  __shared__ double lds[4];
  double s = 0.0, ss = 0.0;
  const long stride = (long)gridDim.x * blockDim.x;
  for (long i = (long)blockIdx.x * blockDim.x + threadIdx.x; i < n; i += stride) {
    double a = x[i];
    s += a;
    ss += a * a;
  }
  s = block_sum(s, lds);
  ss = block_sum(ss, lds);
  if (threadIdx.x == 0) { pA[blockIdx.x] = s; pB[blockIdx.x] = ss; }
}

__global__ void __launch_bounds__(THREADS) k_f1(
    const double* __restrict__ pA, const double* __restrict__ pB, int nblk,
    double n, double* __restrict__ fin) {
  __shared__ double lds[4];
  double s = 0.0, ss = 0.0;
  for (int i = threadIdx.x; i < nblk; i += blockDim.x) { s += pA[i]; ss += pB[i]; }
  s = block_sum(s, lds);
  ss = block_sum(ss, lds);
  if (threadIdx.x == 0) {
    double mean1 = s / n;
    double var1 = (ss - s * s / n) / (n - 1.0);
    fin[0] = mean1;
    fin[1] = 1.0 / sqrt(var1 + EPS);
  }
}

__global__ void __launch_bounds__(THREADS) k_r2(
    const float* __restrict__ x, long n, const double* __restrict__ fin,
    double* __restrict__ pA, double* __restrict__ pB, double* __restrict__ pC) {
  __shared__ double lds[4];
  const float m1 = (float)fin[0];
  const float r1 = (float)fin[1];
  double s = 0.0, ss = 0.0, c = 0.0;
  const long stride = (long)gridDim.x * blockDim.x;
  for (long i = (long)blockIdx.x * blockDim.x + threadIdx.x; i < n; i += stride) {
    float f = x[i];
    float nf = (f - m1) * r1;
    if (nf < THRES && nf > -THRES) { double a = f; s += a; ss += a * a; c += 1.0; }
  }
  s = block_sum(s, lds);
  ss = block_sum(ss, lds);
  c = block_sum(c, lds);
  if (threadIdx.x == 0) { pA[blockIdx.x] = s; pB[blockIdx.x] = ss; pC[blockIdx.x] = c; }
}

__global__ void __launch_bounds__(THREADS) k_f2(
    const double* __restrict__ pA, const double* __restrict__ pB,
    const double* __restrict__ pC, int nblk, double* __restrict__ fin) {
  __shared__ double lds[4];
  double s = 0.0, ss = 0.0, c = 0.0;
  for (int i = threadIdx.x; i < nblk; i += blockDim.x) { s += pA[i]; ss += pB[i]; c += pC[i]; }
  s = block_sum(s, lds);
  ss = block_sum(ss, lds);
  c = block_sum(c, lds);
  if (threadIdx.x == 0) {
    double mean2 = s / c;
    double var2 = (ss - s * s / c) / (c - 1.0);
    fin[2] = mean2;
    fin[3] = 1.0 / sqrt(var2 + EPS);
  }
}

__global__ void __launch_bounds__(THREADS) k_ap(
    const float* __restrict__ x, float* __restrict__ out, long n,
    const double* __restrict__ fin,
    const float* __restrict__ gamma, const float* __restrict__ beta) {
  const float m2 = (float)fin[2];
  const float r2 = (float)fin[3];
  const float g = gamma[0];
  const float bb = beta[0];
  const long stride = (long)gridDim.x * blockDim.x;
  for (long i = (long)blockIdx.x * blockDim.x + threadIdx.x; i < n; i += stride) {
    out[i] = g * (x[i] - m2) * r2 + bb;
  }
}

extern "C" void kernel_launch(void* const* d_in, const int* in_sizes, int n_in,
                              void* d_out, int out_size, void* d_ws, size_t ws_size,
                              hipStream_t stream) {
  const float* x = (const float*)d_in[0];
  const float* gamma = (const float*)d_in[1];
  const float* beta = (const float*)d_in[2];
  float* out = (float*)d_out;
  const long n = (long)in_sizes[0];

  char* base = (char*)d_ws;
  unsigned* bar = (unsigned*)base;                 // BARWORDS uints (~6.2 KB)
  double* fin = (double*)(base + 8192);            // 5 doubles
  double* pS = (double*)(base + 16384);
  double* pSS = pS + NBLK;
  double* pM = pSS + NBLK;
  double* pT = pM + NBLK;
  double* pD = pT + NBLK;
  double* pE = pD + NBLK;
  double* pF = pE + NBLK;
  int* pO = (int*)(pF + NBLK);
  int* counts = pO + NBLK;
  float* slices = (float*)(counts + NBLK);
  size_t needed = (size_t)((char*)(slices + (size_t)NBLK * CAP) - base);

  if (n >= SMALLN && n >= (long)NBLK * 16384 && ws_size >= needed) {
    k_scan<<<NBLK, THREADS, 0, stream>>>(x, n, bar, pS, pSS, pM, pT, pO, counts, slices);
    k_mid<<<1, 1024, 0, stream>>>(n, pS, pSS, pM, pT, pO, counts, slices, fin);
    k_final<<<NBLK, THREADS, 0, stream>>>(x, out, n, gamma, beta, bar, fin, pD, pE, pF);
  } else {
    // small-n scalar pipeline
    int nblk = 64;
    double* sfin = (double*)(base);       // 4 doubles
    double* fA = (double*)(base + 256);
    double* fB = fA + nblk;
    double* fC = fB + nblk;
    k_r1<<<nblk, THREADS, 0, stream>>>(x, n, fA, fB);
    k_f1<<<1, THREADS, 0, stream>>>(fA, fB, nblk, (double)n, sfin);
    k_r2<<<nblk, THREADS, 0, stream>>>(x, n, sfin, fA, fB, fC);
    k_f2<<<1, THREADS, 0, stream>>>(fA, fB, fC, nblk, sfin);
    k_ap<<<nblk, THREADS, 0, stream>>>(x, out, n, sfin, gamma, beta);
  }
}

// Round 9
// 218.001 us; speedup vs baseline: 2.5061x; 1.2255x over previous
//
#include <hip/hip_runtime.h>

#define THREADS 256
#define NBLK 2048          // 8 blocks/CU x 256 CUs
#define MIDBLK 16
#define CHUNK (NBLK / MIDBLK)   // 128
#define GROUPS 64
#define GSIZE (NBLK / GROUPS)   // 32
#define MIRRORS 32
#define DONEA_OFF ((GROUPS + 1 + MIRRORS) * 16)
#define DONEB_OFF (DONEA_OFF + 16)
#define ZERO_WORDS (DONEB_OFF + 16)
#define CAP 128            // power of 2 (shift by 7)
#define EST_ITERS 4        // 4 grid-strides * 1024 floats = 4096-sample estimate
#define EPS 1e-10
#define THRES 4.0f
#define SMALLN (1 << 23)

__device__ __forceinline__ double wave_sum(double v) {
#pragma unroll
  for (int off = 32; off > 0; off >>= 1) v += __shfl_down(v, off, 64);
  return v;
}

// blockDim.x must be 256 (4 waves).
__device__ __forceinline__ double block_sum(double v, double* lds) {
  v = wave_sum(v);
  const int lane = threadIdx.x & 63;
  const int wid = threadIdx.x >> 6;
  __syncthreads();
  if (lane == 0) lds[wid] = v;
  __syncthreads();
  return lds[0] + lds[1] + lds[2] + lds[3];
}

// Hierarchical device-scope grid barrier (FALLBACK PATH ONLY). Single-use.
__device__ __forceinline__ void grid_sync_once(unsigned* bar, int b) {
  __syncthreads();
  if (threadIdx.x == 0) {
    __builtin_amdgcn_fence(__ATOMIC_RELEASE, "agent");
    unsigned* grp = bar + (b / GSIZE) * 16;
    unsigned* root = bar + GROUPS * 16;
    unsigned* mir = bar + (GROUPS + 1) * 16;
    unsigned v = __hip_atomic_fetch_add(grp, 1u, __ATOMIC_ACQ_REL, __HIP_MEMORY_SCOPE_AGENT);
    if (v == GSIZE - 1u) {
      unsigned r = __hip_atomic_fetch_add(root, 1u, __ATOMIC_ACQ_REL, __HIP_MEMORY_SCOPE_AGENT);
      if (r == GROUPS - 1u) {
#pragma unroll
        for (int m = 0; m < MIRRORS; ++m)
          __hip_atomic_store(mir + m * 16, 1u, __ATOMIC_RELEASE, __HIP_MEMORY_SCOPE_AGENT);
      }
    }
    unsigned* mymir = mir + (b & (MIRRORS - 1)) * 16;
    while (__hip_atomic_load(mymir, __ATOMIC_RELAXED, __HIP_MEMORY_SCOPE_AGENT) < 1u) {
      __builtin_amdgcn_s_sleep(32);
    }
    __builtin_amdgcn_fence(__ATOMIC_ACQUIRE, "agent");
  }
  __syncthreads();
}

// ---- K1: grid-stride scan: sum/ss (f64) + LDS candidate collection ----
__global__ void __launch_bounds__(THREADS, 8) k_scan(
    const float* __restrict__ x, long n, unsigned* __restrict__ bar,
    double* __restrict__ pS, double* __restrict__ pSS,
    double* __restrict__ pM, double* __restrict__ pT, int* __restrict__ pO,
    int* __restrict__ counts, float* __restrict__ slices) {
  __shared__ double lds[4];
  __shared__ float lcand[CAP];
  __shared__ int lcnt;
  const int b = blockIdx.x;
  const long nvec = n >> 2;
  const long stride = (long)NBLK * THREADS;
  const long gtid = (long)b * THREADS + threadIdx.x;
  const float4* xv = (const float4*)x;

  if (b == 0) {  // zero fallback-barrier + done-counter state each call
    for (int i = threadIdx.x; i < ZERO_WORDS; i += THREADS) bar[i] = 0u;
  }
  if (threadIdx.x == 0) lcnt = 0;
  __syncthreads();

  // Block-local estimate over the block's first EST_ITERS grid-strides
  double es = 0.0, ess = 0.0, ecnt = 0.0;
  {
    long i = gtid;
#pragma unroll
    for (int k = 0; k < EST_ITERS; ++k, i += stride) {
      if (i < nvec) {
        float4 v = xv[i];
        double a = v.x, bb = v.y, c = v.z, d = v.w;
        es += (a + bb) + (c + d);
        ess += (a * a + bb * bb) + (c * c + d * d);
        ecnt += 4.0;
      }
    }
  }
  es = block_sum(es, lds);
  ess = block_sum(ess, lds);
  ecnt = block_sum(ecnt, lds);
  double mhat = 0.0, th = 0.0;
  int ovf = 0;
  if (ecnt >= 4096.0) {
    mhat = es / ecnt;
    double var = (ess - es * es / ecnt) / (ecnt - 1.0);
    double sig = var > 0.0 ? sqrt(var) : 0.0;
    th = 3.2 * sig;
    if (!(th > 0.0)) ovf = 1;
  } else {
    ovf = 1;
  }
  const float mhf = (float)mhat;
  const float thf = (float)th;

  // Main grid-stride scan (round-2-proven pattern)
  double s = 0.0, ss = 0.0;
  for (long i = gtid; i < nvec; i += stride) {
    float4 v = xv[i];
    double a = v.x, bb = v.y, c = v.z, d = v.w;
    s += (a + bb) + (c + d);
    ss += (a * a + bb * bb) + (c * c + d * d);
    if (fabsf(v.x - mhf) > thf) { int k = atomicAdd(&lcnt, 1); if (k < CAP) lcand[k] = v.x; }
    if (fabsf(v.y - mhf) > thf) { int k = atomicAdd(&lcnt, 1); if (k < CAP) lcand[k] = v.y; }
    if (fabsf(v.z - mhf) > thf) { int k = atomicAdd(&lcnt, 1); if (k < CAP) lcand[k] = v.z; }
    if (fabsf(v.w - mhf) > thf) { int k = atomicAdd(&lcnt, 1); if (k < CAP) lcand[k] = v.w; }
  }
  for (long i = nvec * 4 + gtid; i < n; i += stride) {
    float f = x[i];
    double a = f;
    s += a;
    ss += a * a;
    if (fabsf(f - mhf) > thf) { int k = atomicAdd(&lcnt, 1); if (k < CAP) lcand[k] = f; }
  }
  s = block_sum(s, lds);  // syncs make lcnt/lcand visible
  ss = block_sum(ss, lds);
  if (threadIdx.x == 0) {
    pS[b] = s;
    pSS[b] = ss;
    pM[b] = mhat;
    pT[b] = th;
    pO[b] = (ovf || lcnt > CAP) ? 1 : 0;
    counts[b] = lcnt < CAP ? lcnt : CAP;
  }
  int c = lcnt < CAP ? lcnt : CAP;
  for (int t = threadIdx.x; t < c; t += THREADS)
    slices[(size_t)b * CAP + t] = lcand[t];
}

// ---- K2: 16-block reduce of pS/pSS; last block -> mean1,r1,gs,gss ----
// fin: [0]=mean2 [1]=r2 [2]=fast [3]=mean1 [4]=r1 [5]=gs [6]=gss
__global__ void __launch_bounds__(THREADS) k_mid_a(
    long n, const double* __restrict__ pS, const double* __restrict__ pSS,
    double* __restrict__ q, unsigned* __restrict__ done, double* __restrict__ fin) {
  __shared__ double lds[4];
  const int b = blockIdx.x;  // MIDBLK blocks
  double gs = 0.0, gss = 0.0;
  for (int i = b * CHUNK + threadIdx.x; i < (b + 1) * CHUNK; i += THREADS) {
    gs += pS[i];
    gss += pSS[i];
  }
  gs = block_sum(gs, lds);
  gss = block_sum(gss, lds);
  if (threadIdx.x == 0) {
    q[b] = gs;
    q[MIDBLK + b] = gss;
    __builtin_amdgcn_fence(__ATOMIC_RELEASE, "agent");
    unsigned v = __hip_atomic_fetch_add(done, 1u, __ATOMIC_ACQ_REL, __HIP_MEMORY_SCOPE_AGENT);
    if (v == MIDBLK - 1u) {
      __builtin_amdgcn_fence(__ATOMIC_ACQUIRE, "agent");
      double s = 0.0, ss = 0.0;
      for (int i = 0; i < MIDBLK; ++i) { s += q[i]; ss += q[MIDBLK + i]; }
      const double nd = (double)n;
      double mean1 = s / nd;
      double var1 = (ss - s * s / nd) / (nd - 1.0);
      fin[3] = mean1;
      fin[4] = 1.0 / sqrt(var1 + EPS);
      fin[5] = s;
      fin[6] = ss;
    }
  }
}

// ---- K3: 16-block coverage check + outlier gather; last block -> mean2,r2,fast ----
__global__ void __launch_bounds__(THREADS) k_mid_b(
    long n, const double* __restrict__ pM, const double* __restrict__ pT,
    const int* __restrict__ pO, const int* __restrict__ counts,
    const float* __restrict__ slices,
    double* __restrict__ q, unsigned* __restrict__ done, double* __restrict__ fin) {
  __shared__ double lds[4];
  const int b = blockIdx.x;
  const double mean1 = fin[3];
  const double r1d = fin[4];
  const float m1f = (float)mean1;
  const float r1f = (float)r1d;

  double bad = 0.0;
  for (int i = b * CHUNK + threadIdx.x; i < (b + 1) * CHUNK; i += THREADS) {
    double cond = (pT[i] + fabs(mean1 - pM[i])) * r1d;
    if (pO[i] != 0 || !(cond < 3.999)) bad += 1.0;
  }
  // Coalesced gather over this block's slice chunk (64 KB)
  double os = 0.0, oss = 0.0, oc = 0.0;
  const int i0 = b * CHUNK * CAP;
  const int i1 = (b + 1) * CHUNK * CAP;
  for (int idx = i0 + threadIdx.x; idx < i1; idx += THREADS) {
    int sl = idx >> 7;        // /CAP
    int j = idx & (CAP - 1);  // %CAP
    int c = counts[sl];
    if (c > CAP) c = CAP;
    if (j < c) {
      float v = slices[idx];
      float nf = (v - m1f) * r1f;
      if (!(nf < THRES && nf > -THRES)) {  // exact reference rule complement
        double a = v;
        os += a;
        oss += a * a;
        oc += 1.0;
      }
    }
  }
  bad = block_sum(bad, lds);
  os = block_sum(os, lds);
  oss = block_sum(oss, lds);
  oc = block_sum(oc, lds);
  if (threadIdx.x == 0) {
    q[b] = bad;
    q[MIDBLK + b] = os;
    q[2 * MIDBLK + b] = oss;
    q[3 * MIDBLK + b] = oc;
    __builtin_amdgcn_fence(__ATOMIC_RELEASE, "agent");
    unsigned v = __hip_atomic_fetch_add(done, 1u, __ATOMIC_ACQ_REL, __HIP_MEMORY_SCOPE_AGENT);
    if (v == MIDBLK - 1u) {
      __builtin_amdgcn_fence(__ATOMIC_ACQUIRE, "agent");
      double tb = 0.0, tos = 0.0, toss = 0.0, toc = 0.0;
      for (int i = 0; i < MIDBLK; ++i) {
        tb += q[i];
        tos += q[MIDBLK + i];
        toss += q[2 * MIDBLK + i];
        toc += q[3 * MIDBLK + i];
      }
      const bool fast = (tb == 0.0);
      if (fast) {
        const double nd = (double)n;
        double s2 = fin[5] - tos;
        double ss2 = fin[6] - toss;
        double c2 = nd - toc;
        double mean2 = s2 / c2;
        double var2 = (ss2 - s2 * s2 / c2) / (c2 - 1.0);
        fin[0] = mean2;
        fin[1] = 1.0 / sqrt(var2 + EPS);
      }
      fin[2] = fast ? 1.0 : 0.0;
    }
  }
}

// ---- K4: apply (fast: pure grid-stride stream; fallback: rescan + barrier) ----
__global__ void __launch_bounds__(THREADS, 8) k_final(
    const float* __restrict__ x, float* __restrict__ out, long n,
    const float* __restrict__ gamma, const float* __restrict__ beta,
    unsigned* __restrict__ bar, const double* __restrict__ fin,
    double* __restrict__ pD, double* __restrict__ pE, double* __restrict__ pF) {
  __shared__ double lds[4];
  const int b = blockIdx.x;
  const long nvec = n >> 2;
  const long stride = (long)NBLK * THREADS;
  const long gtid = (long)b * THREADS + threadIdx.x;
  const float4* xv = (const float4*)x;
  const bool fast = (fin[2] != 0.0);

  double mean2, r2d;
  if (fast) {
    mean2 = fin[0];
    r2d = fin[1];
  } else {
    // Fallback: full masked rescan + one grid barrier (never taken in practice)
    const float m1f = (float)fin[3];
    const float r1f = (float)fin[4];
    double os = 0.0, oss = 0.0, oc = 0.0;
    for (long i = gtid; i < nvec; i += stride) {
      float4 v = xv[i];
      float nf;
      nf = (v.x - m1f) * r1f;
      if (nf < THRES && nf > -THRES) { double a = v.x; os += a; oss += a * a; oc += 1.0; }
      nf = (v.y - m1f) * r1f;
      if (nf < THRES && nf > -THRES) { double a = v.y; os += a; oss += a * a; oc += 1.0; }
      nf = (v.z - m1f) * r1f;
      if (nf < THRES && nf > -THRES) { double a = v.z; os += a; oss += a * a; oc += 1.0; }
      nf = (v.w - m1f) * r1f;
      if (nf < THRES && nf > -THRES) { double a = v.w; os += a; oss += a * a; oc += 1.0; }
    }
    for (long i = nvec * 4 + gtid; i < n; i += stride) {
      float f = x[i];
      float nf = (f - m1f) * r1f;
      if (nf < THRES && nf > -THRES) { double a = f; os += a; oss += a * a; oc += 1.0; }
    }
    os = block_sum(os, lds);
    oss = block_sum(oss, lds);
    oc = block_sum(oc, lds);
    if (threadIdx.x == 0) { pD[b] = os; pE[b] = oss; pF[b] = oc; }
    grid_sync_once(bar, b);
    double t1 = 0.0, t2 = 0.0, t3 = 0.0;
    for (int i = threadIdx.x; i < NBLK; i += THREADS) { t1 += pD[i]; t2 += pE[i]; t3 += pF[i]; }
    double s2 = block_sum(t1, lds);
    double ss2 = block_sum(t2, lds);
    double c2 = block_sum(t3, lds);
    mean2 = s2 / c2;
    double var2 = (ss2 - s2 * s2 / c2) / (c2 - 1.0);
    r2d = 1.0 / sqrt(var2 + EPS);
  }

  const float m2f = (float)mean2;
  const float r2f = (float)r2d;
  const float g = gamma[0];
  const float bb = beta[0];
  float4* ov = (float4*)out;
  for (long i = gtid; i < nvec; i += stride) {
    float4 v = xv[i];
    float4 t;
    t.x = g * (v.x - m2f) * r2f + bb;
    t.y = g * (v.y - m2f) * r2f + bb;
    t.z = g * (v.z - m2f) * r2f + bb;
    t.w = g * (v.w - m2f) * r2f + bb;
    ov[i] = t;
  }
  for (long i = nvec * 4 + gtid; i < n; i += stride) {
    out[i] = g * (x[i] - m2f) * r2f + bb;
  }
}

// ---------------- small-n fallback pipeline (scalar, robust) ----------------
__global__ void __launch_bounds__(THREADS) k_r1(
    const float* __restrict__ x, long n, double* __restrict__ pA, double* __restrict__ pB) {
  __shared__ double lds[4];
  double s = 0.0, ss = 0.0;
  const long stride = (long)gridDim.x * blockDim.x;
  for (long i = (long)blockIdx.x * blockDim.x + threadIdx.x; i < n; i += stride) {
    double a = x[i];
    s += a;
    ss += a * a;
  }
  s = block_sum(s, lds);
  ss = block_sum(ss, lds);
  if (threadIdx.x == 0) { pA[blockIdx.x] = s; pB[blockIdx.x] = ss; }
}

__global__ void __launch_bounds__(THREADS) k_f1(
    const double* __restrict__ pA, const double* __restrict__ pB, int nblk,
    double n, double* __restrict__ fin) {
  __shared__ double lds[4];
  double s = 0.0, ss = 0.0;
  for (int i = threadIdx.x; i < nblk; i += blockDim.x) { s += pA[i]; ss += pB[i]; }
  s = block_sum(s, lds);
  ss = block_sum(ss, lds);
  if (threadIdx.x == 0) {
    double mean1 = s / n;
    double var1 = (ss - s * s / n) / (n - 1.0);
    fin[0] = mean1;
    fin[1] = 1.0 / sqrt(var1 + EPS);
  }
}

__global__ void __launch_bounds__(THREADS) k_r2(
    const float* __restrict__ x, long n, const double* __restrict__ fin,
    double* __restrict__ pA, double* __restrict__ pB, double* __restrict__ pC) {
  __shared__ double lds[4];
  const float m1 = (float)fin[0];
  const float r1 = (float)fin[1];
  double s = 0.0, ss = 0.0, c = 0.0;
  const long stride = (long)gridDim.x * blockDim.x;
  for (long i = (long)blockIdx.x * blockDim.x + threadIdx.x; i < n; i += stride) {
    float f = x[i];
    float nf = (f - m1) * r1;
    if (nf < THRES && nf > -THRES) { double a = f; s += a; ss += a * a; c += 1.0; }
  }
  s = block_sum(s, lds);
  ss = block_sum(ss, lds);
  c = block_sum(c, lds);
  if (threadIdx.x == 0) { pA[blockIdx.x] = s; pB[blockIdx.x] = ss; pC[blockIdx.x] = c; }
}

__global__ void __launch_bounds__(THREADS) k_f2(
    const double* __restrict__ pA, const double* __restrict__ pB,
    const double* __restrict__ pC, int nblk, double* __restrict__ fin) {
  __shared__ double lds[4];
  double s = 0.0, ss = 0.0, c = 0.0;
  for (int i = threadIdx.x; i < nblk; i += blockDim.x) { s += pA[i]; ss += pB[i]; c += pC[i]; }
  s = block_sum(s, lds);
  ss = block_sum(ss, lds);
  c = block_sum(c, lds);
  if (threadIdx.x == 0) {
    double mean2 = s / c;
    double var2 = (ss - s * s / c) / (c - 1.0);
    fin[2] = mean2;
    fin[3] = 1.0 / sqrt(var2 + EPS);
  }
}

__global__ void __launch_bounds__(THREADS) k_ap(
    const float* __restrict__ x, float* __restrict__ out, long n,
    const double* __restrict__ fin,
    const float* __restrict__ gamma, const float* __restrict__ beta) {
  const float m2 = (float)fin[2];
  const float r2 = (float)fin[3];
  const float g = gamma[0];
  const float bb = beta[0];
  const long stride = (long)gridDim.x * blockDim.x;
  for (long i = (long)blockIdx.x * blockDim.x + threadIdx.x; i < n; i += stride) {
    out[i] = g * (x[i] - m2) * r2 + bb;
  }
}

extern "C" void kernel_launch(void* const* d_in, const int* in_sizes, int n_in,
                              void* d_out, int out_size, void* d_ws, size_t ws_size,
                              hipStream_t stream) {
  const float* x = (const float*)d_in[0];
  const float* gamma = (const float*)d_in[1];
  const float* beta = (const float*)d_in[2];
  float* out = (float*)d_out;
  const long n = (long)in_sizes[0];

  char* base = (char*)d_ws;
  unsigned* bar = (unsigned*)base;                 // ZERO_WORDS uints (~6.4 KB)
  unsigned* done_a = bar + DONEA_OFF;
  unsigned* done_b = bar + DONEB_OFF;
  double* fin = (double*)(base + 8192);            // 7 doubles
  double* q = (double*)(base + 8192 + 256);        // 64 doubles scratch
  double* pS = (double*)(base + 16384);
  double* pSS = pS + NBLK;
  double* pM = pSS + NBLK;
  double* pT = pM + NBLK;
  double* pD = pT + NBLK;
  double* pE = pD + NBLK;
  double* pF = pE + NBLK;
  int* pO = (int*)(pF + NBLK);
  int* counts = pO + NBLK;
  float* slices = (float*)(counts + NBLK);
  size_t needed = (size_t)((char*)(slices + (size_t)NBLK * CAP) - base);

  if (n >= SMALLN && ws_size >= needed) {
    k_scan<<<NBLK, THREADS, 0, stream>>>(x, n, bar, pS, pSS, pM, pT, pO, counts, slices);
    k_mid_a<<<MIDBLK, THREADS, 0, stream>>>(n, pS, pSS, q, done_a, fin);
    k_mid_b<<<MIDBLK, THREADS, 0, stream>>>(n, pM, pT, pO, counts, slices, q, done_b, fin);
    k_final<<<NBLK, THREADS, 0, stream>>>(x, out, n, gamma, beta, bar, fin, pD, pE, pF);
  } else {
    // small-n scalar pipeline
    int nblk = 64;
    double* sfin = (double*)(base);       // 4 doubles
    double* fA = (double*)(base + 256);
    double* fB = fA + nblk;
    double* fC = fB + nblk;
    k_r1<<<nblk, THREADS, 0, stream>>>(x, n, fA, fB);
    k_f1<<<1, THREADS, 0, stream>>>(fA, fB, nblk, (double)n, sfin);
    k_r2<<<nblk, THREADS, 0, stream>>>(x, n, sfin, fA, fB, fC);
    k_f2<<<1, THREADS, 0, stream>>>(fA, fB, fC, nblk, sfin);
    k_ap<<<nblk, THREADS, 0, stream>>>(x, out, n, sfin, gamma, beta);
  }
}

// Round 10
// 185.813 us; speedup vs baseline: 2.9403x; 1.1732x over previous
//
#include <hip/hip_runtime.h>

#define THREADS 256
#define NBLK 2048          // 8 blocks/CU x 256 CUs
#define MIDBLK 16
#define CHUNK (NBLK / MIDBLK)   // 128
#define GROUPS 64
#define GSIZE (NBLK / GROUPS)   // 32
#define MIRRORS 32
#define DONEA_OFF ((GROUPS + 1 + MIRRORS) * 16)
#define DONEB_OFF (DONEA_OFF + 16)
#define ZERO_WORDS (DONEB_OFF + 16)
#define CAP 128            // power of 2 (shift by 7)
#define EST_ITERS 4        // 4 grid-strides * 1024 floats = 4096-sample estimate
#define EPS 1e-10
#define THRES 4.0f
#define SMALLN (1 << 23)

typedef float vf4 __attribute__((ext_vector_type(4)));

__device__ __forceinline__ double wave_sum(double v) {
#pragma unroll
  for (int off = 32; off > 0; off >>= 1) v += __shfl_down(v, off, 64);
  return v;
}

// blockDim.x must be 256 (4 waves).
__device__ __forceinline__ double block_sum(double v, double* lds) {
  v = wave_sum(v);
  const int lane = threadIdx.x & 63;
  const int wid = threadIdx.x >> 6;
  __syncthreads();
  if (lane == 0) lds[wid] = v;
  __syncthreads();
  return lds[0] + lds[1] + lds[2] + lds[3];
}

// Hierarchical device-scope grid barrier (FALLBACK PATH ONLY). Single-use.
__device__ __forceinline__ void grid_sync_once(unsigned* bar, int b) {
  __syncthreads();
  if (threadIdx.x == 0) {
    __builtin_amdgcn_fence(__ATOMIC_RELEASE, "agent");
    unsigned* grp = bar + (b / GSIZE) * 16;
    unsigned* root = bar + GROUPS * 16;
    unsigned* mir = bar + (GROUPS + 1) * 16;
    unsigned v = __hip_atomic_fetch_add(grp, 1u, __ATOMIC_ACQ_REL, __HIP_MEMORY_SCOPE_AGENT);
    if (v == GSIZE - 1u) {
      unsigned r = __hip_atomic_fetch_add(root, 1u, __ATOMIC_ACQ_REL, __HIP_MEMORY_SCOPE_AGENT);
      if (r == GROUPS - 1u) {
#pragma unroll
        for (int m = 0; m < MIRRORS; ++m)
          __hip_atomic_store(mir + m * 16, 1u, __ATOMIC_RELEASE, __HIP_MEMORY_SCOPE_AGENT);
      }
    }
    unsigned* mymir = mir + (b & (MIRRORS - 1)) * 16;
    while (__hip_atomic_load(mymir, __ATOMIC_RELAXED, __HIP_MEMORY_SCOPE_AGENT) < 1u) {
      __builtin_amdgcn_s_sleep(32);
    }
    __builtin_amdgcn_fence(__ATOMIC_ACQUIRE, "agent");
  }
  __syncthreads();
}

// ---- K1: grid-stride scan: sum/ss (f64) + LDS candidate collection ----
__global__ void __launch_bounds__(THREADS, 8) k_scan(
    const float* __restrict__ x, long n, unsigned* __restrict__ bar,
    double* __restrict__ pS, double* __restrict__ pSS,
    double* __restrict__ pM, double* __restrict__ pT, int* __restrict__ pO,
    int* __restrict__ counts, float* __restrict__ slices) {
  __shared__ double lds[4];
  __shared__ float lcand[CAP];
  __shared__ int lcnt;
  const int b = blockIdx.x;
  const long nvec = n >> 2;
  const long stride = (long)NBLK * THREADS;
  const long gtid = (long)b * THREADS + threadIdx.x;
  const float4* xv = (const float4*)x;

  if (b == 0) {  // zero fallback-barrier + done-counter state each call
    for (int i = threadIdx.x; i < ZERO_WORDS; i += THREADS) bar[i] = 0u;
  }
  if (threadIdx.x == 0) lcnt = 0;
  __syncthreads();

  // Block-local estimate over the block's first EST_ITERS grid-strides
  double es = 0.0, ess = 0.0, ecnt = 0.0;
  {
    long i = gtid;
#pragma unroll
    for (int k = 0; k < EST_ITERS; ++k, i += stride) {
      if (i < nvec) {
        float4 v = xv[i];
        double a = v.x, bb = v.y, c = v.z, d = v.w;
        es += (a + bb) + (c + d);
        ess += (a * a + bb * bb) + (c * c + d * d);
        ecnt += 4.0;
      }
    }
  }
  es = block_sum(es, lds);
  ess = block_sum(ess, lds);
  ecnt = block_sum(ecnt, lds);
  double mhat = 0.0, th = 0.0;
  int ovf = 0;
  if (ecnt >= 4096.0) {
    mhat = es / ecnt;
    double var = (ess - es * es / ecnt) / (ecnt - 1.0);
    double sig = var > 0.0 ? sqrt(var) : 0.0;
    th = 3.2 * sig;
    if (!(th > 0.0)) ovf = 1;
  } else {
    ovf = 1;
  }
  const float mhf = (float)mhat;
  const float thf = (float)th;

  // Main grid-stride scan
  double s = 0.0, ss = 0.0;
  for (long i = gtid; i < nvec; i += stride) {
    float4 v = xv[i];
    double a = v.x, bb = v.y, c = v.z, d = v.w;
    s += (a + bb) + (c + d);
    ss += (a * a + bb * bb) + (c * c + d * d);
    if (fabsf(v.x - mhf) > thf) { int k = atomicAdd(&lcnt, 1); if (k < CAP) lcand[k] = v.x; }
    if (fabsf(v.y - mhf) > thf) { int k = atomicAdd(&lcnt, 1); if (k < CAP) lcand[k] = v.y; }
    if (fabsf(v.z - mhf) > thf) { int k = atomicAdd(&lcnt, 1); if (k < CAP) lcand[k] = v.z; }
    if (fabsf(v.w - mhf) > thf) { int k = atomicAdd(&lcnt, 1); if (k < CAP) lcand[k] = v.w; }
  }
  for (long i = nvec * 4 + gtid; i < n; i += stride) {
    float f = x[i];
    double a = f;
    s += a;
    ss += a * a;
    if (fabsf(f - mhf) > thf) { int k = atomicAdd(&lcnt, 1); if (k < CAP) lcand[k] = f; }
  }
  s = block_sum(s, lds);  // syncs make lcnt/lcand visible
  ss = block_sum(ss, lds);
  if (threadIdx.x == 0) {
    pS[b] = s;
    pSS[b] = ss;
    pM[b] = mhat;
    pT[b] = th;
    pO[b] = (ovf || lcnt > CAP) ? 1 : 0;
    counts[b] = lcnt < CAP ? lcnt : CAP;
  }
  int c = lcnt < CAP ? lcnt : CAP;
  for (int t = threadIdx.x; t < c; t += THREADS)
    slices[(size_t)b * CAP + t] = lcand[t];
}

// ---- K2: 16-block reduce of pS/pSS; last block -> mean1,r1,gs,gss ----
// fin: [0]=mean2 [1]=r2 [2]=fast [3]=mean1 [4]=r1 [5]=gs [6]=gss
__global__ void __launch_bounds__(THREADS) k_mid_a(
    long n, const double* __restrict__ pS, const double* __restrict__ pSS,
    double* __restrict__ q, unsigned* __restrict__ done, double* __restrict__ fin) {
  __shared__ double lds[4];
  const int b = blockIdx.x;  // MIDBLK blocks
  double gs = 0.0, gss = 0.0;
  for (int i = b * CHUNK + threadIdx.x; i < (b + 1) * CHUNK; i += THREADS) {
    gs += pS[i];
    gss += pSS[i];
  }
  gs = block_sum(gs, lds);
  gss = block_sum(gss, lds);
  if (threadIdx.x == 0) {
    q[b] = gs;
    q[MIDBLK + b] = gss;
    __builtin_amdgcn_fence(__ATOMIC_RELEASE, "agent");
    unsigned v = __hip_atomic_fetch_add(done, 1u, __ATOMIC_ACQ_REL, __HIP_MEMORY_SCOPE_AGENT);
    if (v == MIDBLK - 1u) {
      __builtin_amdgcn_fence(__ATOMIC_ACQUIRE, "agent");
      double s = 0.0, ss = 0.0;
      for (int i = 0; i < MIDBLK; ++i) { s += q[i]; ss += q[MIDBLK + i]; }
      const double nd = (double)n;
      double mean1 = s / nd;
      double var1 = (ss - s * s / nd) / (nd - 1.0);
      fin[3] = mean1;
      fin[4] = 1.0 / sqrt(var1 + EPS);
      fin[5] = s;
      fin[6] = ss;
    }
  }
}

// ---- K3: 16-block coverage check + outlier gather; last block -> mean2,r2,fast ----
__global__ void __launch_bounds__(THREADS) k_mid_b(
    long n, const double* __restrict__ pM, const double* __restrict__ pT,
    const int* __restrict__ pO, const int* __restrict__ counts,
    const float* __restrict__ slices,
    double* __restrict__ q, unsigned* __restrict__ done, double* __restrict__ fin) {
  __shared__ double lds[4];
  const int b = blockIdx.x;
  const double mean1 = fin[3];
  const double r1d = fin[4];
  const float m1f = (float)mean1;
  const float r1f = (float)r1d;

  double bad = 0.0;
  for (int i = b * CHUNK + threadIdx.x; i < (b + 1) * CHUNK; i += THREADS) {
    double cond = (pT[i] + fabs(mean1 - pM[i])) * r1d;
    if (pO[i] != 0 || !(cond < 3.999)) bad += 1.0;
  }
  // Coalesced gather over this block's slice chunk (64 KB)
  double os = 0.0, oss = 0.0, oc = 0.0;
  const int i0 = b * CHUNK * CAP;
  const int i1 = (b + 1) * CHUNK * CAP;
  for (int idx = i0 + threadIdx.x; idx < i1; idx += THREADS) {
    int sl = idx >> 7;        // /CAP
    int j = idx & (CAP - 1);  // %CAP
    int c = counts[sl];
    if (c > CAP) c = CAP;
    if (j < c) {
      float v = slices[idx];
      float nf = (v - m1f) * r1f;
      if (!(nf < THRES && nf > -THRES)) {  // exact reference rule complement
        double a = v;
        os += a;
        oss += a * a;
        oc += 1.0;
      }
    }
  }
  bad = block_sum(bad, lds);
  os = block_sum(os, lds);
  oss = block_sum(oss, lds);
  oc = block_sum(oc, lds);
  if (threadIdx.x == 0) {
    q[b] = bad;
    q[MIDBLK + b] = os;
    q[2 * MIDBLK + b] = oss;
    q[3 * MIDBLK + b] = oc;
    __builtin_amdgcn_fence(__ATOMIC_RELEASE, "agent");
    unsigned v = __hip_atomic_fetch_add(done, 1u, __ATOMIC_ACQ_REL, __HIP_MEMORY_SCOPE_AGENT);
    if (v == MIDBLK - 1u) {
      __builtin_amdgcn_fence(__ATOMIC_ACQUIRE, "agent");
      double tb = 0.0, tos = 0.0, toss = 0.0, toc = 0.0;
      for (int i = 0; i < MIDBLK; ++i) {
        tb += q[i];
        tos += q[MIDBLK + i];
        toss += q[2 * MIDBLK + i];
        toc += q[3 * MIDBLK + i];
      }
      const bool fast = (tb == 0.0);
      if (fast) {
        const double nd = (double)n;
        double s2 = fin[5] - tos;
        double ss2 = fin[6] - toss;
        double c2 = nd - toc;
        double mean2 = s2 / c2;
        double var2 = (ss2 - s2 * s2 / c2) / (c2 - 1.0);
        fin[0] = mean2;
        fin[1] = 1.0 / sqrt(var2 + EPS);
      }
      fin[2] = fast ? 1.0 : 0.0;
    }
  }
}

// ---- K4: apply (fast: grid-stride stream, NT stores keep x IC-resident) ----
__global__ void __launch_bounds__(THREADS, 8) k_final(
    const float* __restrict__ x, float* __restrict__ out, long n,
    const float* __restrict__ gamma, const float* __restrict__ beta,
    unsigned* __restrict__ bar, const double* __restrict__ fin,
    double* __restrict__ pD, double* __restrict__ pE, double* __restrict__ pF) {
  __shared__ double lds[4];
  const int b = blockIdx.x;
  const long nvec = n >> 2;
  const long stride = (long)NBLK * THREADS;
  const long gtid = (long)b * THREADS + threadIdx.x;
  const float4* xv = (const float4*)x;
  const bool fast = (fin[2] != 0.0);

  double mean2, r2d;
  if (fast) {
    mean2 = fin[0];
    r2d = fin[1];
  } else {
    // Fallback: full masked rescan + one grid barrier (never taken in practice)
    const float m1f = (float)fin[3];
    const float r1f = (float)fin[4];
    double os = 0.0, oss = 0.0, oc = 0.0;
    for (long i = gtid; i < nvec; i += stride) {
      float4 v = xv[i];
      float nf;
      nf = (v.x - m1f) * r1f;
      if (nf < THRES && nf > -THRES) { double a = v.x; os += a; oss += a * a; oc += 1.0; }
      nf = (v.y - m1f) * r1f;
      if (nf < THRES && nf > -THRES) { double a = v.y; os += a; oss += a * a; oc += 1.0; }
      nf = (v.z - m1f) * r1f;
      if (nf < THRES && nf > -THRES) { double a = v.z; os += a; oss += a * a; oc += 1.0; }
      nf = (v.w - m1f) * r1f;
      if (nf < THRES && nf > -THRES) { double a = v.w; os += a; oss += a * a; oc += 1.0; }
    }
    for (long i = nvec * 4 + gtid; i < n; i += stride) {
      float f = x[i];
      float nf = (f - m1f) * r1f;
      if (nf < THRES && nf > -THRES) { double a = f; os += a; oss += a * a; oc += 1.0; }
    }
    os = block_sum(os, lds);
    oss = block_sum(oss, lds);
    oc = block_sum(oc, lds);
    if (threadIdx.x == 0) { pD[b] = os; pE[b] = oss; pF[b] = oc; }
    grid_sync_once(bar, b);
    double t1 = 0.0, t2 = 0.0, t3 = 0.0;
    for (int i = threadIdx.x; i < NBLK; i += THREADS) { t1 += pD[i]; t2 += pE[i]; t3 += pF[i]; }
    double s2 = block_sum(t1, lds);
    double ss2 = block_sum(t2, lds);
    double c2 = block_sum(t3, lds);
    mean2 = s2 / c2;
    double var2 = (ss2 - s2 * s2 / c2) / (c2 - 1.0);
    r2d = 1.0 / sqrt(var2 + EPS);
  }

  const float m2f = (float)mean2;
  const float r2f = (float)r2d;
  const float g = gamma[0];
  const float bb = beta[0];
  float4* ov = (float4*)out;
  for (long i = gtid; i < nvec; i += stride) {
    float4 v = xv[i];
    vf4 t;
    t.x = g * (v.x - m2f) * r2f + bb;
    t.y = g * (v.y - m2f) * r2f + bb;
    t.z = g * (v.z - m2f) * r2f + bb;
    t.w = g * (v.w - m2f) * r2f + bb;
    __builtin_nontemporal_store(t, (vf4*)&ov[i]);
  }
  for (long i = nvec * 4 + gtid; i < n; i += stride) {
    float t = g * (x[i] - m2f) * r2f + bb;
    __builtin_nontemporal_store(t, &out[i]);
  }
}

// ---------------- small-n fallback pipeline (scalar, robust) ----------------
__global__ void __launch_bounds__(THREADS) k_r1(
    const float* __restrict__ x, long n, double* __restrict__ pA, double* __restrict__ pB) {
  __shared__ double lds[4];
  double s = 0.0, ss = 0.0;
  const long stride = (long)gridDim.x * blockDim.x;
  for (long i = (long)blockIdx.x * blockDim.x + threadIdx.x; i < n; i += stride) {
    double a = x[i];
    s += a;
    ss += a * a;
  }
  s = block_sum(s, lds);
  ss = block_sum(ss, lds);
  if (threadIdx.x == 0) { pA[blockIdx.x] = s; pB[blockIdx.x] = ss; }
}

__global__ void __launch_bounds__(THREADS) k_f1(
    const double* __restrict__ pA, const double* __restrict__ pB, int nblk,
    double n, double* __restrict__ fin) {
  __shared__ double lds[4];
  double s = 0.0, ss = 0.0;
  for (int i = threadIdx.x; i < nblk; i += blockDim.x) { s += pA[i]; ss += pB[i]; }
  s = block_sum(s, lds);
  ss = block_sum(ss, lds);
  if (threadIdx.x == 0) {
    double mean1 = s / n;
    double var1 = (ss - s * s / n) / (n - 1.0);
    fin[0] = mean1;
    fin[1] = 1.0 / sqrt(var1 + EPS);
  }
}

__global__ void __launch_bounds__(THREADS) k_r2(
    const float* __restrict__ x, long n, const double* __restrict__ fin,
    double* __restrict__ pA, double* __restrict__ pB, double* __restrict__ pC) {
  __shared__ double lds[4];
  const float m1 = (float)fin[0];
  const float r1 = (float)fin[1];
  double s = 0.0, ss = 0.0, c = 0.0;
  const long stride = (long)gridDim.x * blockDim.x;
  for (long i = (long)blockIdx.x * blockDim.x + threadIdx.x; i < n; i += stride) {
    float f = x[i];
    float nf = (f - m1) * r1;
    if (nf < THRES && nf > -THRES) { double a = f; s += a; ss += a * a; c += 1.0; }
  }
  s = block_sum(s, lds);
  ss = block_sum(ss, lds);
  c = block_sum(c, lds);
  if (threadIdx.x == 0) { pA[blockIdx.x] = s; pB[blockIdx.x] = ss; pC[blockIdx.x] = c; }
}

__global__ void __launch_bounds__(THREADS) k_f2(
    const double* __restrict__ pA, const double* __restrict__ pB,
    const double* __restrict__ pC, int nblk, double* __restrict__ fin) {
  __shared__ double lds[4];
  double s = 0.0, ss = 0.0, c = 0.0;
  for (int i = threadIdx.x; i < nblk; i += blockDim.x) { s += pA[i]; ss += pB[i]; c += pC[i]; }
  s = block_sum(s, lds);
  ss = block_sum(ss, lds);
  c = block_sum(c, lds);
  if (threadIdx.x == 0) {
    double mean2 = s / c;
    double var2 = (ss - s * s / c) / (c - 1.0);
    fin[2] = mean2;
    fin[3] = 1.0 / sqrt(var2 + EPS);
  }
}

__global__ void __launch_bounds__(THREADS) k_ap(
    const float* __restrict__ x, float* __restrict__ out, long n,
    const double* __restrict__ fin,
    const float* __restrict__ gamma, const float* __restrict__ beta) {
  const float m2 = (float)fin[2];
  const float r2 = (float)fin[3];
  const float g = gamma[0];
  const float bb = beta[0];
  const long stride = (long)gridDim.x * blockDim.x;
  for (long i = (long)blockIdx.x * blockDim.x + threadIdx.x; i < n; i += stride) {
    out[i] = g * (x[i] - m2) * r2 + bb;
  }
}

extern "C" void kernel_launch(void* const* d_in, const int* in_sizes, int n_in,
                              void* d_out, int out_size, void* d_ws, size_t ws_size,
                              hipStream_t stream) {
  const float* x = (const float*)d_in[0];
  const float* gamma = (const float*)d_in[1];
  const float* beta = (const float*)d_in[2];
  float* out = (float*)d_out;
  const long n = (long)in_sizes[0];

  char* base = (char*)d_ws;
  unsigned* bar = (unsigned*)base;                 // ZERO_WORDS uints (~6.4 KB)
  unsigned* done_a = bar + DONEA_OFF;
  unsigned* done_b = bar + DONEB_OFF;
  double* fin = (double*)(base + 8192);            // 7 doubles
  double* q = (double*)(base + 8192 + 256);        // 64 doubles scratch
  double* pS = (double*)(base + 16384);
  double* pSS = pS + NBLK;
  double* pM = pSS + NBLK;
  double* pT = pM + NBLK;
  double* pD = pT + NBLK;
  double* pE = pD + NBLK;
  double* pF = pE + NBLK;
  int* pO = (int*)(pF + NBLK);
  int* counts = pO + NBLK;
  float* slices = (float*)(counts + NBLK);
  size_t needed = (size_t)((char*)(slices + (size_t)NBLK * CAP) - base);

  if (n >= SMALLN && ws_size >= needed) {
    k_scan<<<NBLK, THREADS, 0, stream>>>(x, n, bar, pS, pSS, pM, pT, pO, counts, slices);
    k_mid_a<<<MIDBLK, THREADS, 0, stream>>>(n, pS, pSS, q, done_a, fin);
    k_mid_b<<<MIDBLK, THREADS, 0, stream>>>(n, pM, pT, pO, counts, slices, q, done_b, fin);
    k_final<<<NBLK, THREADS, 0, stream>>>(x, out, n, gamma, beta, bar, fin, pD, pE, pF);
  } else {
    // small-n scalar pipeline
    int nblk = 64;
    double* sfin = (double*)(base);       // 4 doubles
    double* fA = (double*)(base + 256);
    double* fB = fA + nblk;
    double* fC = fB + nblk;
    k_r1<<<nblk, THREADS, 0, stream>>>(x, n, fA, fB);
    k_f1<<<1, THREADS, 0, stream>>>(fA, fB, nblk, (double)n, sfin);
    k_r2<<<nblk, THREADS, 0, stream>>>(x, n, sfin, fA, fB, fC);
    k_f2<<<1, THREADS, 0, stream>>>(fA, fB, fC, nblk, sfin);
    k_ap<<<nblk, THREADS, 0, stream>>>(x, out, n, sfin, gamma, beta);
  }
}